// Round 20
// baseline (918.362 us; speedup 1.0000x reference)
//
#include <hip/hip_runtime.h>
#include <math.h>

#define NTOK 20000
#define NTOKP 20096   // padded to multiple of 128
#define EMB 512
#define HID 1024
#define VD 2048
#define ML 20
#define NBATCH 128
#define KREG 36
#define NSTEP 19
#define XIN_D 2560
#define G3 3072
#define NQH 4096      // pq(1024) + gh(3072) fused N

#define QH_SK 4
#define QH_KPER 256

// int workspace layout (indices into (int*)d_ws)
#define WI_ORDER 0
#define WI_DEC 128
#define WI_BATCH 256
#define WI_OFF 288
#define WI_P 320

typedef short short8v __attribute__((ext_vector_type(8)));
typedef unsigned short ushort8v __attribute__((ext_vector_type(8)));
typedef unsigned short ushort4v __attribute__((ext_vector_type(4)));
typedef float f32x4 __attribute__((ext_vector_type(4)));

static __device__ __forceinline__ float sigmoidf_(float x) { return 1.f / (1.f + expf(-x)); }

static __device__ __forceinline__ unsigned short f2bf(float x) {
    unsigned int b = __float_as_uint(x);
    return (unsigned short)((b + 0x7FFFu + ((b >> 16) & 1u)) >> 16);
}
static __device__ __forceinline__ float bf2f(unsigned short h) {
    return __uint_as_float(((unsigned int)h) << 16);
}

// bijective XCD-grouping swizzle (m204): blocks with consecutive JOB ids land on
// the same XCD, so B-panel sharers hit the same L2.
static __device__ __forceinline__ int xcd_job(int orig, int n) {
    const int q = n >> 3, r = n & 7;
    const int xcd = orig & 7, pos = orig >> 3;
    return (xcd < r ? xcd * (q + 1) : r * (q + 1) + (xcd - r) * q) + pos;
}

// truncation split: x ~= hi + lo to ~2^-16 relative
static __device__ __forceinline__ void split8(const float* __restrict__ p,
                                              ushort8v& hi, ushort8v& lo) {
    float4 a = *(const float4*)p;
    float4 b = *(const float4*)(p + 4);
    float vals[8] = {a.x, a.y, a.z, a.w, b.x, b.y, b.z, b.w};
#pragma unroll
    for (int j = 0; j < 8; ++j) {
        unsigned int bits = __float_as_uint(vals[j]);
        hi[j] = (unsigned short)(bits >> 16);
        float rem = vals[j] - __uint_as_float(bits & 0xFFFF0000u);
        lo[j] = (unsigned short)(__float_as_uint(rem) >> 16);
    }
}

// round-nearest bf16 convert of 8 contiguous f32
static __device__ __forceinline__ ushort8v cvt8(const float* __restrict__ p) {
    float4 a = *(const float4*)p;
    float4 b = *(const float4*)(p + 4);
    ushort8v o;
    o[0] = f2bf(a.x); o[1] = f2bf(a.y); o[2] = f2bf(a.z); o[3] = f2bf(a.w);
    o[4] = f2bf(b.x); o[5] = f2bf(b.y); o[6] = f2bf(b.z); o[7] = f2bf(b.w);
    return o;
}

// ---- shared MFMA inner bodies ----
static __device__ __forceinline__ void mfma_inner_split(const unsigned short* sAh,
                                                        const unsigned short* sAl,
                                                        const unsigned short* sBh,
                                                        const unsigned short* sBl,
                                                        int wm, int wn, int lr, int lq,
                                                        f32x4 acc[2][4]) {
#pragma unroll
    for (int ks = 0; ks < 2; ++ks) {
        short8v ah[2], al[2], bh[4], bl[4];
#pragma unroll
        for (int m = 0; m < 2; ++m) {
            int r = wm + m * 16 + lr;
            int o = r * 64 + (((ks * 4 + lq) ^ (r & 7)) * 8);
            ah[m] = *(const short8v*)(sAh + o);
            al[m] = *(const short8v*)(sAl + o);
        }
#pragma unroll
        for (int n = 0; n < 4; ++n) {
            int r = wn + n * 16 + lr;
            int o = r * 64 + (((ks * 4 + lq) ^ (r & 7)) * 8);
            bh[n] = *(const short8v*)(sBh + o);
            bl[n] = *(const short8v*)(sBl + o);
        }
#pragma unroll
        for (int m = 0; m < 2; ++m) {
#pragma unroll
            for (int n = 0; n < 4; ++n) {
                acc[m][n] = __builtin_amdgcn_mfma_f32_16x16x32_bf16(al[m], bh[n], acc[m][n], 0, 0, 0);
                acc[m][n] = __builtin_amdgcn_mfma_f32_16x16x32_bf16(ah[m], bl[n], acc[m][n], 0, 0, 0);
                acc[m][n] = __builtin_amdgcn_mfma_f32_16x16x32_bf16(ah[m], bh[n], acc[m][n], 0, 0, 0);
            }
        }
    }
}

static __device__ __forceinline__ void mfma_inner_bf16(const unsigned short* sA,
                                                       const unsigned short* sB,
                                                       int wm, int wn, int lr, int lq,
                                                       f32x4 acc[2][4]) {
#pragma unroll
    for (int ks = 0; ks < 2; ++ks) {
        short8v a[2], b[4];
#pragma unroll
        for (int m = 0; m < 2; ++m) {
            int r = wm + m * 16 + lr;
            a[m] = *(const short8v*)(sA + r * 64 + (((ks * 4 + lq) ^ (r & 7)) * 8));
        }
#pragma unroll
        for (int n = 0; n < 4; ++n) {
            int r = wn + n * 16 + lr;
            b[n] = *(const short8v*)(sB + r * 64 + (((ks * 4 + lq) ^ (r & 7)) * 8));
        }
#pragma unroll
        for (int m = 0; m < 2; ++m) {
#pragma unroll
            for (int n = 0; n < 4; ++n) {
                acc[m][n] = __builtin_amdgcn_mfma_f32_16x16x32_bf16(a[m], b[n], acc[m][n], 0, 0, 0);
            }
        }
    }
}

// ---------------------------------------------------------------- prep
__global__ __launch_bounds__(128) void prep_kernel(const int* __restrict__ cap_len,
                                                   int* __restrict__ wsI) {
    __shared__ int cl[NBATCH], sord[NBATCH], sdec[NBATCH], sbat[NSTEP];
    int b = threadIdx.x;
    cl[b] = cap_len[b];
    __syncthreads();
    int my = cl[b], rank = 0;
    for (int j = 0; j < NBATCH; ++j) {
        int o = cl[j];
        rank += (o > my) || (o == my && j < b);
    }
    sord[rank] = b;
    sdec[rank] = my - 1;
    __syncthreads();
    wsI[WI_ORDER + b] = sord[b];
    wsI[WI_DEC + b] = sdec[b];
    if (b < NSTEP) {
        int c = 0;
        for (int s = 0; s < NBATCH; ++s) c += (sdec[s] > b);
        sbat[b] = c;
        wsI[WI_BATCH + b] = c;
    }
    __syncthreads();
    if (b == 0) {
        int run = 0;
        for (int t = 0; t < NSTEP; ++t) { wsI[WI_OFF + t] = run; run += sbat[t]; }
        wsI[WI_P] = run;
    }
}

// ---------------------------------------------------------------- h = 0 (f32 + hi/lo)
__global__ __launch_bounds__(256) void h_init_kernel(float* __restrict__ h,
                                                     unsigned short* __restrict__ h_hi,
                                                     unsigned short* __restrict__ h_lo) {
    int i = blockIdx.x * 256 + threadIdx.x;
    h[i] = 0.f;
    h_hi[i] = 0;
    h_lo[i] = 0;
}

// ---------------------------------------------------------------- gather v by order + RN-split hi/lo
__global__ __launch_bounds__(256) void gather_split_v_kernel(const float* __restrict__ v,
                                                             const int* __restrict__ wsI,
                                                             unsigned short* __restrict__ hi,
                                                             unsigned short* __restrict__ lo) {
    const int r = blockIdx.x;           // 0..4607 : s*36+k
    const int s = r / KREG, k = r % KREG;
    const float* src = v + ((size_t)wsI[WI_ORDER + s] * KREG + k) * VD + threadIdx.x * 8;
    float4 a = *(const float4*)(src);
    float4 b = *(const float4*)(src + 4);
    ushort8v oh, ol;
    float vals[8] = {a.x, a.y, a.z, a.w, b.x, b.y, b.z, b.w};
#pragma unroll
    for (int j = 0; j < 8; ++j) {
        unsigned short h = f2bf(vals[j]);
        oh[j] = h;
        ol[j] = f2bf(vals[j] - bf2f(h));
    }
    size_t off = (size_t)r * VD + threadIdx.x * 8;
    *(ushort8v*)(hi + off) = oh;
    *(ushort8v*)(lo + off) = ol;
}

// ---------------------------------------------------------------- Wfc -> bf16 (padded rows zeroed)
__global__ __launch_bounds__(256) void cvt_wfc_kernel(const float* __restrict__ W,
                                                      unsigned short* __restrict__ dst) {
    size_t i8 = ((size_t)blockIdx.x * 256 + threadIdx.x) * 8;  // over NTOKP*HID
    int row = (int)(i8 >> 10);
    ushort8v o;
    if (row < NTOK) {
        o = cvt8(W + i8);
    } else {
        for (int j = 0; j < 8; ++j) o[j] = 0;
    }
    *(ushort8v*)(dst + i8) = o;
}

// ---------------------------------------------------------------- Wih[:,512:2560] -> bf16 [3072][2048]
__global__ __launch_bounds__(256) void cvt_wih2_kernel(const float* __restrict__ Wih,
                                                       unsigned short* __restrict__ dst) {
    size_t i8 = ((size_t)blockIdx.x * 256 + threadIdx.x) * 8;  // over 3072*2048
    int row = (int)(i8 >> 11);
    int col = (int)(i8 & 2047);
    *(ushort8v*)(dst + i8) = cvt8(Wih + (size_t)row * XIN_D + EMB + col);
}

// ---------------------------------------------------------------- Wv [2048][1024] -> WvT hi/lo [1024][2048]
__global__ __launch_bounds__(256) void trans_split_wv_kernel(const float* __restrict__ W,
                                                             unsigned short* __restrict__ hi,
                                                             unsigned short* __restrict__ lo) {
    __shared__ float t[32][33];
    const int k0 = blockIdx.x * 32, n0 = blockIdx.y * 32;
    const int tx = threadIdx.x & 31, ty = threadIdx.x >> 5;  // ty in [0,8)
#pragma unroll
    for (int i = 0; i < 4; ++i) {
        int r = ty + i * 8;
        t[r][tx] = W[(size_t)(k0 + r) * HID + n0 + tx];
    }
    __syncthreads();
#pragma unroll
    for (int i = 0; i < 4; ++i) {
        int rn = ty + i * 8;
        float x = t[tx][rn];  // = W[k0+tx][n0+rn]
        unsigned short h = f2bf(x);
        unsigned short l = f2bf(x - bf2f(h));
        hi[(size_t)(n0 + rn) * VD + k0 + tx] = h;
        lo[(size_t)(n0 + rn) * VD + k0 + tx] = l;
    }
}

// ---------------------------------------------------------------- Wq [1024][1024] -> Bqh rows 0..1023 (WqT hi/lo)
__global__ __launch_bounds__(256) void trans_split_wq_kernel(const float* __restrict__ W,
                                                             unsigned short* __restrict__ hi,
                                                             unsigned short* __restrict__ lo) {
    __shared__ float t[32][33];
    const int k0 = blockIdx.x * 32, n0 = blockIdx.y * 32;
    const int tx = threadIdx.x & 31, ty = threadIdx.x >> 5;
#pragma unroll
    for (int i = 0; i < 4; ++i) {
        int r = ty + i * 8;
        t[r][tx] = W[(size_t)(k0 + r) * HID + n0 + tx];
    }
    __syncthreads();
#pragma unroll
    for (int i = 0; i < 4; ++i) {
        int rn = ty + i * 8;
        float x = t[tx][rn];  // = W[k0+tx][n0+rn]
        unsigned short h = f2bf(x);
        unsigned short l = f2bf(x - bf2f(h));
        hi[(size_t)(n0 + rn) * HID + k0 + tx] = h;
        lo[(size_t)(n0 + rn) * HID + k0 + tx] = l;
    }
}

// ---------------------------------------------------------------- Whh [3072][1024] -> Bqh rows 1024..4095 (hi/lo)
__global__ __launch_bounds__(256) void split_whh_kernel(const float* __restrict__ W,
                                                        unsigned short* __restrict__ hi,
                                                        unsigned short* __restrict__ lo) {
    size_t i8 = ((size_t)blockIdx.x * 256 + threadIdx.x) * 8;  // over 3072*1024
    ushort8v oh, ol;
    split8(W + i8, oh, ol);
    *(ushort8v*)(hi + i8) = oh;
    *(ushort8v*)(lo + i8) = ol;
}

// ================================================================ MFMA GEMMs
// Tile BM=64 x BN=128, BK=64; 4 waves of 32(M)x64(N).
// LDS: ushort offset row*64 + ((chunk ^ (row&7)) * 8)  (XOR bank swizzle).
// All staged GEMMs software-pipelined: tile k+1's global loads issue before tile k's MFMA.

// ---- pv: pvwbf[row][col] = bf16( relu(vrow . WvT[col] + bv[col]) * wa[col] )
//      576 jobs = nt(8) x mr(72), XCD-grouped so B-panel sharers co-locate.
__global__ __launch_bounds__(256) void pv_mfma_kernel(const unsigned short* __restrict__ Ahi,
                                                      const unsigned short* __restrict__ Alo,
                                                      const unsigned short* __restrict__ Bhi,
                                                      const unsigned short* __restrict__ Blo,
                                                      const float* __restrict__ bv,
                                                      const float* __restrict__ wa,
                                                      unsigned short* __restrict__ pvwbf) {
    const int job = xcd_job(blockIdx.x, 8 * 72);
    const int nt = job / 72, mr = job % 72;
    const int m0 = mr * 64, n0 = nt * 128;
    __shared__ unsigned short sAh[64 * 64], sAl[64 * 64];
    __shared__ unsigned short sBh[128 * 64], sBl[128 * 64];
    const int tid = threadIdx.x;
    const int w = tid >> 6, l = tid & 63;
    const int wm = (w >> 1) * 32, wn = (w & 1) * 64;
    const int lr = l & 15, lq = l >> 4;
    const int s8 = tid & 7, ar0 = tid >> 3;
    const int slot = (s8 ^ (ar0 & 7)) * 8;
    const size_t a0Off = (size_t)(m0 + ar0) * VD + s8 * 8;
    const size_t a1Off = a0Off + (size_t)32 * VD;
    const size_t b0Off = (size_t)(n0 + ar0) * VD + s8 * 8;

    f32x4 acc[2][4] = {};
    // prologue: prefetch tile 0
    ushort8v rah0 = *(const ushort8v*)(Ahi + a0Off);
    ushort8v ral0 = *(const ushort8v*)(Alo + a0Off);
    ushort8v rah1 = *(const ushort8v*)(Ahi + a1Off);
    ushort8v ral1 = *(const ushort8v*)(Alo + a1Off);
    ushort8v rbh0 = *(const ushort8v*)(Bhi + b0Off);
    ushort8v rbl0 = *(const ushort8v*)(Blo + b0Off);
    ushort8v rbh1 = *(const ushort8v*)(Bhi + b0Off + (size_t)32 * VD);
    ushort8v rbl1 = *(const ushort8v*)(Blo + b0Off + (size_t)32 * VD);
    ushort8v rbh2 = *(const ushort8v*)(Bhi + b0Off + (size_t)64 * VD);
    ushort8v rbl2 = *(const ushort8v*)(Blo + b0Off + (size_t)64 * VD);
    ushort8v rbh3 = *(const ushort8v*)(Bhi + b0Off + (size_t)96 * VD);
    ushort8v rbl3 = *(const ushort8v*)(Blo + b0Off + (size_t)96 * VD);

    for (int k0 = 0; k0 < VD; k0 += 64) {
        __syncthreads();
        *(ushort8v*)(sAh + ar0 * 64 + slot) = rah0;
        *(ushort8v*)(sAl + ar0 * 64 + slot) = ral0;
        *(ushort8v*)(sAh + (ar0 + 32) * 64 + slot) = rah1;
        *(ushort8v*)(sAl + (ar0 + 32) * 64 + slot) = ral1;
        *(ushort8v*)(sBh + ar0 * 64 + slot) = rbh0;
        *(ushort8v*)(sBl + ar0 * 64 + slot) = rbl0;
        *(ushort8v*)(sBh + (ar0 + 32) * 64 + slot) = rbh1;
        *(ushort8v*)(sBl + (ar0 + 32) * 64 + slot) = rbl1;
        *(ushort8v*)(sBh + (ar0 + 64) * 64 + slot) = rbh2;
        *(ushort8v*)(sBl + (ar0 + 64) * 64 + slot) = rbl2;
        *(ushort8v*)(sBh + (ar0 + 96) * 64 + slot) = rbh3;
        *(ushort8v*)(sBl + (ar0 + 96) * 64 + slot) = rbl3;
        __syncthreads();
        if (k0 + 64 < VD) {
            const int kn = k0 + 64;
            rah0 = *(const ushort8v*)(Ahi + a0Off + kn);
            ral0 = *(const ushort8v*)(Alo + a0Off + kn);
            rah1 = *(const ushort8v*)(Ahi + a1Off + kn);
            ral1 = *(const ushort8v*)(Alo + a1Off + kn);
            rbh0 = *(const ushort8v*)(Bhi + b0Off + kn);
            rbl0 = *(const ushort8v*)(Blo + b0Off + kn);
            rbh1 = *(const ushort8v*)(Bhi + b0Off + (size_t)32 * VD + kn);
            rbl1 = *(const ushort8v*)(Blo + b0Off + (size_t)32 * VD + kn);
            rbh2 = *(const ushort8v*)(Bhi + b0Off + (size_t)64 * VD + kn);
            rbl2 = *(const ushort8v*)(Blo + b0Off + (size_t)64 * VD + kn);
            rbh3 = *(const ushort8v*)(Bhi + b0Off + (size_t)96 * VD + kn);
            rbl3 = *(const ushort8v*)(Blo + b0Off + (size_t)96 * VD + kn);
        }
        mfma_inner_split(sAh, sAl, sBh, sBl, wm, wn, lr, lq, acc);
    }

#pragma unroll
    for (int m = 0; m < 2; ++m) {
        const int row = m0 + wm + m * 16 + lq * 4;
#pragma unroll
        for (int n = 0; n < 4; ++n) {
            const int col = n0 + wn + n * 16 + lr;
            const float bb = bv[col], ww = wa[col];
#pragma unroll
            for (int i = 0; i < 4; ++i)
                pvwbf[(size_t)(row + i) * HID + col] = f2bf(fmaxf(acc[m][n][i] + bb, 0.f) * ww);
        }
    }
}

// ---- pvw2: PVW2[(s*36+k)][j] = bf16( vhi[row] . wih2bf[j] )  pure bf16, 24 KB LDS.
//      1728 jobs = nt(24) x mr(72), XCD-grouped.
__global__ __launch_bounds__(256) void pvw2_mfma_kernel(const unsigned short* __restrict__ vhi,
                                                        const unsigned short* __restrict__ w2,
                                                        unsigned short* __restrict__ pvw2) {
    const int job = xcd_job(blockIdx.x, 24 * 72);
    const int nt = job / 72, mr = job % 72;
    const int m0 = mr * 64, n0 = nt * 128;
    __shared__ unsigned short sA[64 * 64];
    __shared__ unsigned short sB[128 * 64];
    const int tid = threadIdx.x;
    const int w = tid >> 6, l = tid & 63;
    const int wm = (w >> 1) * 32, wn = (w & 1) * 64;
    const int lr = l & 15, lq = l >> 4;
    const int s8 = tid & 7, ar0 = tid >> 3;
    const int slot = (s8 ^ (ar0 & 7)) * 8;
    const size_t aBase = (size_t)(m0 + ar0) * VD + s8 * 8;
    const size_t bBase = (size_t)(n0 + ar0) * VD + s8 * 8;

    f32x4 acc[2][4] = {};
    // prologue: prefetch tile 0
    ushort8v ra0 = *(const ushort8v*)(vhi + aBase);
    ushort8v ra1 = *(const ushort8v*)(vhi + aBase + (size_t)32 * VD);
    ushort8v rb0 = *(const ushort8v*)(w2 + bBase);
    ushort8v rb1 = *(const ushort8v*)(w2 + bBase + (size_t)32 * VD);
    ushort8v rb2 = *(const ushort8v*)(w2 + bBase + (size_t)64 * VD);
    ushort8v rb3 = *(const ushort8v*)(w2 + bBase + (size_t)96 * VD);

    for (int k0 = 0; k0 < VD; k0 += 64) {
        __syncthreads();
        *(ushort8v*)(sA + ar0 * 64 + slot) = ra0;
        *(ushort8v*)(sA + (ar0 + 32) * 64 + slot) = ra1;
        *(ushort8v*)(sB + ar0 * 64 + slot) = rb0;
        *(ushort8v*)(sB + (ar0 + 32) * 64 + slot) = rb1;
        *(ushort8v*)(sB + (ar0 + 64) * 64 + slot) = rb2;
        *(ushort8v*)(sB + (ar0 + 96) * 64 + slot) = rb3;
        __syncthreads();
        if (k0 + 64 < VD) {
            const int kn = k0 + 64;
            ra0 = *(const ushort8v*)(vhi + aBase + kn);
            ra1 = *(const ushort8v*)(vhi + aBase + (size_t)32 * VD + kn);
            rb0 = *(const ushort8v*)(w2 + bBase + kn);
            rb1 = *(const ushort8v*)(w2 + bBase + (size_t)32 * VD + kn);
            rb2 = *(const ushort8v*)(w2 + bBase + (size_t)64 * VD + kn);
            rb3 = *(const ushort8v*)(w2 + bBase + (size_t)96 * VD + kn);
        }
        mfma_inner_bf16(sA, sB, wm, wn, lr, lq, acc);
    }

#pragma unroll
    for (int m = 0; m < 2; ++m) {
        const int row = m0 + wm + m * 16 + lq * 4;
#pragma unroll
        for (int n = 0; n < 4; ++n) {
            const int col = n0 + wn + n * 16 + lr;
#pragma unroll
            for (int i = 0; i < 4; ++i)
                pvw2[(size_t)(row + i) * G3 + col] = f2bf(acc[m][n][i]);
        }
    }
}

// ---- giE: giE[(t*128+s)][j] = bf16( emb[caption[order[s],t]] . Wih[j, 0:512] )  split-3
__global__ __launch_bounds__(256) void giE_mfma_kernel(const float* __restrict__ emb,
                                                       const int* __restrict__ caption,
                                                       const float* __restrict__ Wih,
                                                       const int* __restrict__ wsI,
                                                       unsigned short* __restrict__ giE) {
    const int m0 = blockIdx.y * 64;   // over 2432
    const int n0 = blockIdx.x * 128;  // over 3072
    __shared__ unsigned short sAh[64 * 64], sAl[64 * 64];
    __shared__ unsigned short sBh[128 * 64], sBl[128 * 64];
    const int tid = threadIdx.x;
    const int w = tid >> 6, l = tid & 63;
    const int wm = (w >> 1) * 32, wn = (w & 1) * 64;
    const int lr = l & 15, lq = l >> 4;
    const int s8 = tid & 7, ar0 = tid >> 3;
    const int slot = (s8 ^ (ar0 & 7)) * 8;
    const int gm0 = m0 + ar0, gm1 = gm0 + 32;
    const int tok0 = caption[wsI[WI_ORDER + (gm0 & 127)] * ML + (gm0 >> 7)];
    const int tok1 = caption[wsI[WI_ORDER + (gm1 & 127)] * ML + (gm1 >> 7)];
    const float* aR0 = emb + (size_t)tok0 * EMB + s8 * 8;
    const float* aR1 = emb + (size_t)tok1 * EMB + s8 * 8;
    const float* bR0 = Wih + (size_t)(n0 + ar0) * XIN_D + s8 * 8;

    f32x4 acc[2][4] = {};

    for (int k0 = 0; k0 < EMB; k0 += 64) {
        ushort8v ah0, al0, ah1, al1;
        split8(aR0 + k0, ah0, al0);
        split8(aR1 + k0, ah1, al1);
        ushort8v bh_[4], bl_[4];
#pragma unroll
        for (int j = 0; j < 4; ++j)
            split8(bR0 + (size_t)j * 32 * XIN_D + k0, bh_[j], bl_[j]);
        __syncthreads();
        *(ushort8v*)(sAh + ar0 * 64 + slot) = ah0;
        *(ushort8v*)(sAl + ar0 * 64 + slot) = al0;
        *(ushort8v*)(sAh + (ar0 + 32) * 64 + slot) = ah1;
        *(ushort8v*)(sAl + (ar0 + 32) * 64 + slot) = al1;
#pragma unroll
        for (int j = 0; j < 4; ++j) {
            *(ushort8v*)(sBh + (ar0 + j * 32) * 64 + slot) = bh_[j];
            *(ushort8v*)(sBl + (ar0 + j * 32) * 64 + slot) = bl_[j];
        }
        __syncthreads();
        mfma_inner_split(sAh, sAl, sBh, sBl, wm, wn, lr, lq, acc);
    }

#pragma unroll
    for (int m = 0; m < 2; ++m) {
        const int row = m0 + wm + m * 16 + lq * 4;
#pragma unroll
        for (int n = 0; n < 4; ++n) {
            const int col = n0 + wn + n * 16 + lr;
#pragma unroll
            for (int i = 0; i < 4; ++i)
                giE[(size_t)(row + i) * G3 + col] = f2bf(acc[m][n][i]);
        }
    }
}

// ---- qh(t): split-K=4 partials into qhp (256 blocks); h pre-split hi/lo; pipelined
__global__ __launch_bounds__(256) void qh_kernel(const unsigned short* __restrict__ h_hi,
                                                 const unsigned short* __restrict__ h_lo,
                                                 const unsigned short* __restrict__ Bhi,
                                                 const unsigned short* __restrict__ Blo,
                                                 const int* __restrict__ wsI, int tq,
                                                 float* __restrict__ qhp) {
    if (tq >= NSTEP) return;
    __shared__ unsigned short lds[24576];  // 48 KB
    const int tid = threadIdx.x;
    const int w = tid >> 6, l = tid & 63;
    const int wm = (w >> 1) * 32, wn = (w & 1) * 64;
    const int lr = l & 15, lq = l >> 4;
    const int s8 = tid & 7, ar0 = tid >> 3;
    const int slot = (s8 ^ (ar0 & 7)) * 8;
    const int bx = blockIdx.x;
    const int nt = bx & 31, mt = (bx >> 5) & 1, sl = bx >> 6;  // sl in [0,4)
    const int nb = wsI[WI_BATCH + tq];
    const int m0 = mt * 64;
    if (m0 >= nb) return;
    const int n0 = nt * 128;
    const int kb = sl * QH_KPER;
    unsigned short* sAh = lds;
    unsigned short* sAl = lds + 4096;
    unsigned short* sBh = lds + 8192;
    unsigned short* sBl = lds + 16384;
    const size_t aOff = (size_t)(m0 + ar0) * HID + s8 * 8;
    const size_t bOff = (size_t)(n0 + ar0) * HID + s8 * 8;

    f32x4 acc[2][4] = {};
    // prologue: prefetch tile kb
    ushort8v rah0 = *(const ushort8v*)(h_hi + aOff + kb);
    ushort8v ral0 = *(const ushort8v*)(h_lo + aOff + kb);
    ushort8v rah1 = *(const ushort8v*)(h_hi + aOff + (size_t)32 * HID + kb);
    ushort8v ral1 = *(const ushort8v*)(h_lo + aOff + (size_t)32 * HID + kb);
    ushort8v rbh0 = *(const ushort8v*)(Bhi + bOff + kb);
    ushort8v rbl0 = *(const ushort8v*)(Blo + bOff + kb);
    ushort8v rbh1 = *(const ushort8v*)(Bhi + bOff + (size_t)32 * HID + kb);
    ushort8v rbl1 = *(const ushort8v*)(Blo + bOff + (size_t)32 * HID + kb);
    ushort8v rbh2 = *(const ushort8v*)(Bhi + bOff + (size_t)64 * HID + kb);
    ushort8v rbl2 = *(const ushort8v*)(Blo + bOff + (size_t)64 * HID + kb);
    ushort8v rbh3 = *(const ushort8v*)(Bhi + bOff + (size_t)96 * HID + kb);
    ushort8v rbl3 = *(const ushort8v*)(Blo + bOff + (size_t)96 * HID + kb);

    for (int k0 = kb; k0 < kb + QH_KPER; k0 += 64) {
        __syncthreads();
        *(ushort8v*)(sAh + ar0 * 64 + slot) = rah0;
        *(ushort8v*)(sAl + ar0 * 64 + slot) = ral0;
        *(ushort8v*)(sAh + (ar0 + 32) * 64 + slot) = rah1;
        *(ushort8v*)(sAl + (ar0 + 32) * 64 + slot) = ral1;
        *(ushort8v*)(sBh + ar0 * 64 + slot) = rbh0;
        *(ushort8v*)(sBl + ar0 * 64 + slot) = rbl0;
        *(ushort8v*)(sBh + (ar0 + 32) * 64 + slot) = rbh1;
        *(ushort8v*)(sBl + (ar0 + 32) * 64 + slot) = rbl1;
        *(ushort8v*)(sBh + (ar0 + 64) * 64 + slot) = rbh2;
        *(ushort8v*)(sBl + (ar0 + 64) * 64 + slot) = rbl2;
        *(ushort8v*)(sBh + (ar0 + 96) * 64 + slot) = rbh3;
        *(ushort8v*)(sBl + (ar0 + 96) * 64 + slot) = rbl3;
        __syncthreads();
        if (k0 + 64 < kb + QH_KPER) {
            const int kn = k0 + 64;
            rah0 = *(const ushort8v*)(h_hi + aOff + kn);
            ral0 = *(const ushort8v*)(h_lo + aOff + kn);
            rah1 = *(const ushort8v*)(h_hi + aOff + (size_t)32 * HID + kn);
            ral1 = *(const ushort8v*)(h_lo + aOff + (size_t)32 * HID + kn);
            rbh0 = *(const ushort8v*)(Bhi + bOff + kn);
            rbl0 = *(const ushort8v*)(Blo + bOff + kn);
            rbh1 = *(const ushort8v*)(Bhi + bOff + (size_t)32 * HID + kn);
            rbl1 = *(const ushort8v*)(Blo + bOff + (size_t)32 * HID + kn);
            rbh2 = *(const ushort8v*)(Bhi + bOff + (size_t)64 * HID + kn);
            rbl2 = *(const ushort8v*)(Blo + bOff + (size_t)64 * HID + kn);
            rbh3 = *(const ushort8v*)(Bhi + bOff + (size_t)96 * HID + kn);
            rbl3 = *(const ushort8v*)(Blo + bOff + (size_t)96 * HID + kn);
        }
        mfma_inner_split(sAh, sAl, sBh, sBl, wm, wn, lr, lq, acc);
    }
#pragma unroll
    for (int m = 0; m < 2; ++m) {
        const int row = m0 + wm + m * 16 + lq * 4;
#pragma unroll
        for (int n = 0; n < 4; ++n) {
            const int col = n0 + wn + n * 16 + lr;
#pragma unroll
            for (int i = 0; i < 4; ++i) {
                int r = row + i;
                if (r < nb) qhp[((size_t)(sl * NBATCH) + r) * NQH + col] = acc[m][n][i];
            }
        }
    }
}

// ---- batched logits over all steps, BN=128, XCD-grouped, DOUBLE-BUFFERED LDS:
//      write tile k+1 into the idle buffer while MFMA reads the live one.
//      ONE barrier per K-tile; loads for k+2 issued a full iteration ahead.
__global__ __launch_bounds__(256) void big_logits_kernel(const unsigned short* __restrict__ hbf_all,
                                                         const unsigned short* __restrict__ Wbf,
                                                         const float* __restrict__ bfc,
                                                         const int* __restrict__ wsI,
                                                         float* __restrict__ out) {
    const int job = xcd_job(blockIdx.x, 38 * 157);
    const int nt = job / 38;
    const int x = job % 38;
    const int t = x >> 1, mt = x & 1;
    const int nb = wsI[WI_BATCH + t];
    const int m0 = mt * 64;
    if (m0 >= nb) return;
    const int n0 = nt * 128;
    __shared__ unsigned short lds[2 * 12288];  // 48 KB double-buffered (A 8KB + B 16KB per buf)
    const int tid = threadIdx.x;
    const int w = tid >> 6, l = tid & 63;
    const int wm = (w >> 1) * 32, wn = (w & 1) * 64;
    const int lr = l & 15, lq = l >> 4;
    const int s8 = tid & 7, ar0 = tid >> 3;
    const int slot = (s8 ^ (ar0 & 7)) * 8;
    const unsigned short* hbf = hbf_all + (size_t)t * NBATCH * HID;
    const size_t aBase = (size_t)(m0 + ar0) * HID + s8 * 8;
    const size_t bBase = (size_t)(n0 + ar0) * HID + s8 * 8;

    f32x4 acc[2][4] = {};
    // prologue: tile 0 -> regs -> LDS buf0; tile 1 -> regs
    ushort8v ra0 = *(const ushort8v*)(hbf + aBase);
    ushort8v ra1 = *(const ushort8v*)(hbf + aBase + (size_t)32 * HID);
    ushort8v rb0 = *(const ushort8v*)(Wbf + bBase);
    ushort8v rb1 = *(const ushort8v*)(Wbf + bBase + (size_t)32 * HID);
    ushort8v rb2 = *(const ushort8v*)(Wbf + bBase + (size_t)64 * HID);
    ushort8v rb3 = *(const ushort8v*)(Wbf + bBase + (size_t)96 * HID);
    {
        unsigned short* sA = lds;
        unsigned short* sB = lds + 4096;
        *(ushort8v*)(sA + ar0 * 64 + slot) = ra0;
        *(ushort8v*)(sA + (ar0 + 32) * 64 + slot) = ra1;
        *(ushort8v*)(sB + ar0 * 64 + slot) = rb0;
        *(ushort8v*)(sB + (ar0 + 32) * 64 + slot) = rb1;
        *(ushort8v*)(sB + (ar0 + 64) * 64 + slot) = rb2;
        *(ushort8v*)(sB + (ar0 + 96) * 64 + slot) = rb3;
    }
    {
        const int kn = 64;
        ra0 = *(const ushort8v*)(hbf + aBase + kn);
        ra1 = *(const ushort8v*)(hbf + aBase + (size_t)32 * HID + kn);
        rb0 = *(const ushort8v*)(Wbf + bBase + kn);
        rb1 = *(const ushort8v*)(Wbf + bBase + (size_t)32 * HID + kn);
        rb2 = *(const ushort8v*)(Wbf + bBase + (size_t)64 * HID + kn);
        rb3 = *(const ushort8v*)(Wbf + bBase + (size_t)96 * HID + kn);
    }
    __syncthreads();

    // main loop: at iter idx, regs hold tile idx+1; write it to the idle buffer,
    // issue loads for tile idx+2, MFMA on the live buffer, one barrier.
    for (int idx = 0; idx < 16; ++idx) {
        unsigned short* cbuf = lds + (idx & 1) * 12288;
        unsigned short* nbuf = lds + ((idx + 1) & 1) * 12288;
        if (idx + 1 < 16) {
            unsigned short* sA = nbuf;
            unsigned short* sB = nbuf + 4096;
            *(ushort8v*)(sA + ar0 * 64 + slot) = ra0;
            *(ushort8v*)(sA + (ar0 + 32) * 64 + slot) = ra1;
            *(ushort8v*)(sB + ar0 * 64 + slot) = rb0;
            *(ushort8v*)(sB + (ar0 + 32) * 64 + slot) = rb1;
            *(ushort8v*)(sB + (ar0 + 64) * 64 + slot) = rb2;
            *(ushort8v*)(sB + (ar0 + 96) * 64 + slot) = rb3;
        }
        if (idx + 2 < 16) {
            const int kn = (idx + 2) * 64;
            ra0 = *(const ushort8v*)(hbf + aBase + kn);
            ra1 = *(const ushort8v*)(hbf + aBase + (size_t)32 * HID + kn);
            rb0 = *(const ushort8v*)(Wbf + bBase + kn);
            rb1 = *(const ushort8v*)(Wbf + bBase + (size_t)32 * HID + kn);
            rb2 = *(const ushort8v*)(Wbf + bBase + (size_t)64 * HID + kn);
            rb3 = *(const ushort8v*)(Wbf + bBase + (size_t)96 * HID + kn);
        }
        mfma_inner_bf16(cbuf, cbuf + 4096, wm, wn, lr, lq, acc);
        __syncthreads();
    }
    const int offt = wsI[WI_OFF + t];
#pragma unroll
    for (int m = 0; m < 2; ++m) {
        const int row = m0 + wm + m * 16 + lq * 4;
#pragma unroll
        for (int n = 0; n < 4; ++n) {
            const int col = n0 + wn + n * 16 + lr;
            if (col < NTOK) {
                const float bb = bfc[col];
#pragma unroll
                for (int i = 0; i < 4; ++i) {
                    int r = row + i;
                    if (r < nb) out[(size_t)(offt + r) * NTOK + col] = acc[m][n][i] + bb;
                }
            }
        }
    }
}

// ---------------------------------------------------------------- AG: scores + softmax + gisum + GRU
//      grid = 2*NBATCH: block (s, half); phases A-C duplicated per half (cheap),
//      phase D covers HID/2 columns -> 2x CU coverage on the dominant pvw2 stream.
__global__ __launch_bounds__(256) void ag_kernel(const float* __restrict__ qhp,
                                                 const float* __restrict__ bq,
                                                 const unsigned short* __restrict__ pvwbf,
                                                 const unsigned short* __restrict__ pvw2,
                                                 const unsigned short* __restrict__ giE,
                                                 const float* __restrict__ bih,
                                                 const float* __restrict__ bhh,
                                                 const int* __restrict__ wsI, int t,
                                                 float* __restrict__ h,
                                                 unsigned short* __restrict__ h_hi,
                                                 unsigned short* __restrict__ h_lo,
                                                 unsigned short* __restrict__ hbf_all) {
    const int nb = wsI[WI_BATCH + t];
    const int s = blockIdx.x >> 1;
    const int half = blockIdx.x & 1;
    if (s >= nb) return;
    const int tid = threadIdx.x;
    __shared__ float pq_s[HID];
    __shared__ float sc[64];
    unsigned short* hbfA = hbf_all + (size_t)t * NBATCH * HID;

    // phase A: pq = relu(bq + sum of QH_SK partials)
    for (int j = tid; j < HID; j += 256) {
        float a = bq[j];
#pragma unroll
        for (int sl = 0; sl < QH_SK; ++sl) a += qhp[(size_t)(sl * NBATCH + s) * NQH + j];
        pq_s[j] = fmaxf(a, 0.f);
    }
    __syncthreads();

    // phase B: 36 attention scores (vectorized ushort8 loads)
    const int w = tid >> 6, lane = tid & 63;
    for (int k = w; k < KREG; k += 4) {
        const unsigned short* pr = pvwbf + ((size_t)s * KREG + k) * HID;
        float a = 0.f;
#pragma unroll
        for (int c = 0; c < 2; ++c) {
            const int hh = (lane + 64 * c) * 8;
            ushort8v p8 = *(const ushort8v*)(pr + hh);
            float4 q0 = *(const float4*)(pq_s + hh);
            float4 q1 = *(const float4*)(pq_s + hh + 4);
            a += bf2f(p8[0]) * q0.x + bf2f(p8[1]) * q0.y + bf2f(p8[2]) * q0.z + bf2f(p8[3]) * q0.w;
            a += bf2f(p8[4]) * q1.x + bf2f(p8[5]) * q1.y + bf2f(p8[6]) * q1.z + bf2f(p8[7]) * q1.w;
        }
#pragma unroll
        for (int o = 32; o > 0; o >>= 1) a += __shfl_down(a, o);
        if (lane == 0) sc[k] = a;
    }
    __syncthreads();

    // phase C: softmax over 36
    if (tid < 64) {
        float x = (tid < KREG) ? sc[tid] : -1e30f;
        float m = x;
#pragma unroll
        for (int o = 32; o > 0; o >>= 1) m = fmaxf(m, __shfl_xor(m, o));
        float e = (tid < KREG) ? expf(x - m) : 0.f;
        float sum = e;
#pragma unroll
        for (int o = 32; o > 0; o >>= 1) sum += __shfl_xor(sum, o);
        if (tid < KREG) sc[tid] = e / sum;
    }
    __syncthreads();

    // phase D (tid<128): gisum (giE + att-weighted PVW2) + GRU gates over this half's 512 cols
    if (tid < 128) {
        const int j0 = half * 512 + tid * 4;
        float accR[4], accZ[4], accN[4];
        {
            const unsigned short* ge = giE + ((size_t)(t * NBATCH) + s) * G3;
            ushort4v r4 = *(const ushort4v*)(ge + j0);
            ushort4v z4 = *(const ushort4v*)(ge + HID + j0);
            ushort4v n4 = *(const ushort4v*)(ge + 2 * HID + j0);
#pragma unroll
            for (int i = 0; i < 4; ++i) {
                accR[i] = bf2f(r4[i]);
                accZ[i] = bf2f(z4[i]);
                accN[i] = bf2f(n4[i]);
            }
        }
#pragma unroll 4
        for (int k = 0; k < KREG; ++k) {
            const unsigned short* p = pvw2 + ((size_t)s * KREG + k) * G3;
            const float ak = sc[k];
            ushort4v r4 = *(const ushort4v*)(p + j0);
            ushort4v z4 = *(const ushort4v*)(p + HID + j0);
            ushort4v n4 = *(const ushort4v*)(p + 2 * HID + j0);
#pragma unroll
            for (int i = 0; i < 4; ++i) {
                accR[i] += ak * bf2f(r4[i]);
                accZ[i] += ak * bf2f(z4[i]);
                accN[i] += ak * bf2f(n4[i]);
            }
        }
#pragma unroll
        for (int i = 0; i < 4; ++i) {
            const int j = j0 + i;
            float ghr = bhh[j], ghz = bhh[j + HID], ghn = bhh[j + 2 * HID];
#pragma unroll
            for (int sl = 0; sl < QH_SK; ++sl) {
                const float* p = qhp + (size_t)(sl * NBATCH + s) * NQH + HID;
                ghr += p[j]; ghz += p[j + HID]; ghn += p[j + 2 * HID];
            }
            float gir = bih[j] + accR[i];
            float giz = bih[j + HID] + accZ[i];
            float gin = bih[j + 2 * HID] + accN[i];
            float r = sigmoidf_(gir + ghr);
            float z = sigmoidf_(giz + ghz);
            float n = tanhf(gin + r * ghn);
            size_t idx = (size_t)s * HID + j;
            float hn = (1.f - z) * n + z * h[idx];
            h[idx] = hn;
            hbfA[idx] = f2bf(hn);
            // trunc-hi + RN-lo split (identical to split8 numerics) for next qh
            unsigned int bits = __float_as_uint(hn);
            unsigned short hh = (unsigned short)(bits >> 16);
            h_hi[idx] = hh;
            h_lo[idx] = f2bf(hn - __uint_as_float(bits & 0xFFFF0000u));
        }
    }
}

// ---------------------------------------------------------------- in-place softmax over time dim
__global__ __launch_bounds__(256) void softmax_time_kernel(const int* __restrict__ wsI,
                                                           float* __restrict__ out) {
    const int n = blockIdx.x * 256 + threadIdx.x;
    if (n >= NTOK) return;
    const int s = blockIdx.y;
    const int dc = wsI[WI_DEC + s];
    float l[NSTEP];
    float m = 0.f;
#pragma unroll
    for (int t = 0; t < NSTEP; ++t) {
        float val = -1e30f;
        if (t < dc) val = out[(size_t)(wsI[WI_OFF + t] + s) * NTOK + n];
        l[t] = val;
        m = fmaxf(m, val);
    }
    float denom = (float)(ML - dc) * expf(-m);
    float e[NSTEP];
#pragma unroll
    for (int t = 0; t < NSTEP; ++t) {
        e[t] = expf(l[t] - m);
        if (t < dc) denom += e[t];
    }
    const float inv = 1.f / denom;
#pragma unroll
    for (int t = 0; t < NSTEP; ++t)
        if (t < dc) {
            float val = e[t] * inv;
            __builtin_nontemporal_store(val, &out[(size_t)(wsI[WI_OFF + t] + s) * NTOK + n]);
        }
}

// ---------------------------------------------------------------- targets
__global__ __launch_bounds__(128) void target_kernel(const int* __restrict__ caption,
                                                     const int* __restrict__ wsI,
                                                     float* __restrict__ out) {
    const int t = blockIdx.x, s = threadIdx.x;
    if (s < wsI[WI_BATCH + t]) {
        size_t base = (size_t)wsI[WI_P] * NTOK;
        out[base + wsI[WI_OFF + t] + s] = (float)caption[wsI[WI_ORDER + s] * ML + t + 1];
    }
}

// ---------------------------------------------------------------- launch
extern "C" void kernel_launch(void* const* d_in, const int* in_sizes, int n_in,
                              void* d_out, int out_size, void* d_ws, size_t ws_size,
                              hipStream_t stream) {
    const float* v       = (const float*)d_in[0];
    const int*   caption = (const int*)d_in[1];
    const int*   cap_len = (const int*)d_in[2];
    const float* emb     = (const float*)d_in[3];
    const float* Wv      = (const float*)d_in[4];
    const float* bv      = (const float*)d_in[5];
    const float* Wq      = (const float*)d_in[6];
    const float* bq      = (const float*)d_in[7];
    const float* wa      = (const float*)d_in[8];
    // d_in[9] = ba: dropped (softmax shift-invariant)
    const float* Wih     = (const float*)d_in[10];
    const float* Whh     = (const float*)d_in[11];
    const float* bih     = (const float*)d_in[12];
    const float* bhh     = (const float*)d_in[13];
    const float* Wfc     = (const float*)d_in[14];
    const float* bfc     = (const float*)d_in[15];
    float* out = (float*)d_out;

    // workspace layout (~117 MB, lifetime-overlaid regions X/Y/Z)
    int* wsI = (int*)d_ws;
    unsigned short* base    = (unsigned short*)((char*)d_ws + 4096);
    unsigned short* pvwbf   = base;                       //  4,718,592 us
    unsigned short* pvw2    = pvwbf + 4718592;            // 14,155,776 us
    unsigned short* hbf_all = pvw2 + 14155776;            //  2,490,368 us (19 steps)
    unsigned short* X       = hbf_all + 2490368;          // 20,578,304 us (NTOKP*HID)
    unsigned short* Y       = X + 20578304;               //  8,388,608 us
    unsigned short* Z       = Y + 8388608;                //  7,471,104 us
    float* h = (float*)(Z + 7471104);                     //    131,072 f
    unsigned short* h_hi = (unsigned short*)(h + 131072); //    131,072 us
    unsigned short* h_lo = h_hi + 131072;                 //    131,072 us
    // region views (disjoint lifetimes):
    unsigned short* vhi    = X;              // pre-phase (until pvw2 done)
    unsigned short* vlo    = X + 9437184;
    float*          qhp    = (float*)X;      // loop phase (4*128*4096 f = 8 MB)
    unsigned short* Wfcbf  = X;              // post-loop (cvt_wfc kills qhp)
    unsigned short* wvthi  = Y;              // pre-phase (pv)
    unsigned short* wvtlo  = Y + 2097152;
    unsigned short* bqh_hi = Y;              // from trans_wq on (kills wvt)
    unsigned short* bqh_lo = Y + 4194304;
    unsigned short* wih2bf = Z;              // pre-phase (pvw2)
    unsigned short* giE    = Z;              // from giE_mfma on (kills wih2bf)

    prep_kernel<<<1, 128, 0, stream>>>(cap_len, wsI);
    h_init_kernel<<<(NBATCH * HID) / 256, 256, 0, stream>>>(h, h_hi, h_lo);
    gather_split_v_kernel<<<NBATCH * KREG, 256, 0, stream>>>(v, wsI, vhi, vlo);
    trans_split_wv_kernel<<<dim3(VD / 32, HID / 32), 256, 0, stream>>>(Wv, wvthi, wvtlo);
    cvt_wih2_kernel<<<(G3 * VD / 8) / 256, 256, 0, stream>>>(Wih, wih2bf);
    pv_mfma_kernel<<<8 * 72, 256, 0, stream>>>(vhi, vlo, wvthi, wvtlo, bv, wa, pvwbf);
    pvw2_mfma_kernel<<<24 * 72, 256, 0, stream>>>(vhi, wih2bf, pvw2);
    // wvt dead -> bqh; wih2bf dead -> giE; vhi/vlo dead -> qhp
    trans_split_wq_kernel<<<dim3(HID / 32, HID / 32), 256, 0, stream>>>(Wq, bqh_hi, bqh_lo);
    split_whh_kernel<<<(G3 * HID / 8) / 256, 256, 0, stream>>>(
        Whh, bqh_hi + (size_t)HID * HID, bqh_lo + (size_t)HID * HID);
    giE_mfma_kernel<<<dim3(G3 / 128, (NSTEP * NBATCH) / 64), 256, 0, stream>>>(
        emb, caption, Wih, wsI, giE);

    // prologue qh(0) (h == 0 -> zero partials)
    qh_kernel<<<64 * QH_SK, 256, 0, stream>>>(h_hi, h_lo, bqh_hi, bqh_lo, wsI, 0, qhp);

    for (int t = 0; t < NSTEP; ++t) {
        ag_kernel<<<NBATCH * 2, 256, 0, stream>>>(qhp, bq, pvwbf, pvw2, giE, bih, bhh, wsI, t,
                                                  h, h_hi, h_lo, hbf_all);
        if (t + 1 < NSTEP)
            qh_kernel<<<64 * QH_SK, 256, 0, stream>>>(h_hi, h_lo, bqh_hi, bqh_lo, wsI, t + 1, qhp);
    }

    // qhp dead -> Wfcbf
    cvt_wfc_kernel<<<((size_t)NTOKP * HID / 8) / 256, 256, 0, stream>>>(Wfc, Wfcbf);
    big_logits_kernel<<<38 * 157, 256, 0, stream>>>(hbf_all, Wfcbf, bfc, wsI, out);
    softmax_time_kernel<<<dim3((NTOK + 255) / 256, NBATCH), 256, 0, stream>>>(wsI, out);
    target_kernel<<<NSTEP, 128, 0, stream>>>(caption, wsI, out);
    (void)in_sizes; (void)n_in; (void)out_size; (void)ws_size;
}

// Round 21
// 903.183 us; speedup vs baseline: 1.0168x; 1.0168x over previous
//
#include <hip/hip_runtime.h>
#include <math.h>

#define NTOK 20000
#define NTOKP 20096   // padded to multiple of 128
#define EMB 512
#define HID 1024
#define VD 2048
#define ML 20
#define NBATCH 128
#define KREG 36
#define NSTEP 19
#define XIN_D 2560
#define G3 3072
#define NQH 4096      // pq(1024) + gh(3072) fused N

#define QH_SK 4
#define QH_KPER 256

// int workspace layout (indices into (int*)d_ws)
#define WI_ORDER 0
#define WI_DEC 128
#define WI_BATCH 256
#define WI_OFF 288
#define WI_P 320

typedef short short8v __attribute__((ext_vector_type(8)));
typedef unsigned short ushort8v __attribute__((ext_vector_type(8)));
typedef unsigned short ushort4v __attribute__((ext_vector_type(4)));
typedef float f32x4 __attribute__((ext_vector_type(4)));

static __device__ __forceinline__ float sigmoidf_(float x) { return 1.f / (1.f + expf(-x)); }

static __device__ __forceinline__ unsigned short f2bf(float x) {
    unsigned int b = __float_as_uint(x);
    return (unsigned short)((b + 0x7FFFu + ((b >> 16) & 1u)) >> 16);
}
static __device__ __forceinline__ float bf2f(unsigned short h) {
    return __uint_as_float(((unsigned int)h) << 16);
}

// bijective XCD-grouping swizzle (m204): blocks with consecutive JOB ids land on
// the same XCD, so B-panel sharers hit the same L2.
static __device__ __forceinline__ int xcd_job(int orig, int n) {
    const int q = n >> 3, r = n & 7;
    const int xcd = orig & 7, pos = orig >> 3;
    return (xcd < r ? xcd * (q + 1) : r * (q + 1) + (xcd - r) * q) + pos;
}

// truncation split: x ~= hi + lo to ~2^-16 relative
static __device__ __forceinline__ void split8(const float* __restrict__ p,
                                              ushort8v& hi, ushort8v& lo) {
    float4 a = *(const float4*)p;
    float4 b = *(const float4*)(p + 4);
    float vals[8] = {a.x, a.y, a.z, a.w, b.x, b.y, b.z, b.w};
#pragma unroll
    for (int j = 0; j < 8; ++j) {
        unsigned int bits = __float_as_uint(vals[j]);
        hi[j] = (unsigned short)(bits >> 16);
        float rem = vals[j] - __uint_as_float(bits & 0xFFFF0000u);
        lo[j] = (unsigned short)(__float_as_uint(rem) >> 16);
    }
}

// round-nearest bf16 convert of 8 contiguous f32
static __device__ __forceinline__ ushort8v cvt8(const float* __restrict__ p) {
    float4 a = *(const float4*)p;
    float4 b = *(const float4*)(p + 4);
    ushort8v o;
    o[0] = f2bf(a.x); o[1] = f2bf(a.y); o[2] = f2bf(a.z); o[3] = f2bf(a.w);
    o[4] = f2bf(b.x); o[5] = f2bf(b.y); o[6] = f2bf(b.z); o[7] = f2bf(b.w);
    return o;
}

// ---- shared MFMA inner bodies ----
static __device__ __forceinline__ void mfma_inner_split(const unsigned short* sAh,
                                                        const unsigned short* sAl,
                                                        const unsigned short* sBh,
                                                        const unsigned short* sBl,
                                                        int wm, int wn, int lr, int lq,
                                                        f32x4 acc[2][4]) {
#pragma unroll
    for (int ks = 0; ks < 2; ++ks) {
        short8v ah[2], al[2], bh[4], bl[4];
#pragma unroll
        for (int m = 0; m < 2; ++m) {
            int r = wm + m * 16 + lr;
            int o = r * 64 + (((ks * 4 + lq) ^ (r & 7)) * 8);
            ah[m] = *(const short8v*)(sAh + o);
            al[m] = *(const short8v*)(sAl + o);
        }
#pragma unroll
        for (int n = 0; n < 4; ++n) {
            int r = wn + n * 16 + lr;
            int o = r * 64 + (((ks * 4 + lq) ^ (r & 7)) * 8);
            bh[n] = *(const short8v*)(sBh + o);
            bl[n] = *(const short8v*)(sBl + o);
        }
#pragma unroll
        for (int m = 0; m < 2; ++m) {
#pragma unroll
            for (int n = 0; n < 4; ++n) {
                acc[m][n] = __builtin_amdgcn_mfma_f32_16x16x32_bf16(al[m], bh[n], acc[m][n], 0, 0, 0);
                acc[m][n] = __builtin_amdgcn_mfma_f32_16x16x32_bf16(ah[m], bl[n], acc[m][n], 0, 0, 0);
                acc[m][n] = __builtin_amdgcn_mfma_f32_16x16x32_bf16(ah[m], bh[n], acc[m][n], 0, 0, 0);
            }
        }
    }
}

static __device__ __forceinline__ void mfma_inner_bf16(const unsigned short* sA,
                                                       const unsigned short* sB,
                                                       int wm, int wn, int lr, int lq,
                                                       f32x4 acc[2][4]) {
#pragma unroll
    for (int ks = 0; ks < 2; ++ks) {
        short8v a[2], b[4];
#pragma unroll
        for (int m = 0; m < 2; ++m) {
            int r = wm + m * 16 + lr;
            a[m] = *(const short8v*)(sA + r * 64 + (((ks * 4 + lq) ^ (r & 7)) * 8));
        }
#pragma unroll
        for (int n = 0; n < 4; ++n) {
            int r = wn + n * 16 + lr;
            b[n] = *(const short8v*)(sB + r * 64 + (((ks * 4 + lq) ^ (r & 7)) * 8));
        }
#pragma unroll
        for (int m = 0; m < 2; ++m) {
#pragma unroll
            for (int n = 0; n < 4; ++n) {
                acc[m][n] = __builtin_amdgcn_mfma_f32_16x16x32_bf16(a[m], b[n], acc[m][n], 0, 0, 0);
            }
        }
    }
}

// ---------------------------------------------------------------- prep
__global__ __launch_bounds__(128) void prep_kernel(const int* __restrict__ cap_len,
                                                   int* __restrict__ wsI) {
    __shared__ int cl[NBATCH], sord[NBATCH], sdec[NBATCH], sbat[NSTEP];
    int b = threadIdx.x;
    cl[b] = cap_len[b];
    __syncthreads();
    int my = cl[b], rank = 0;
    for (int j = 0; j < NBATCH; ++j) {
        int o = cl[j];
        rank += (o > my) || (o == my && j < b);
    }
    sord[rank] = b;
    sdec[rank] = my - 1;
    __syncthreads();
    wsI[WI_ORDER + b] = sord[b];
    wsI[WI_DEC + b] = sdec[b];
    if (b < NSTEP) {
        int c = 0;
        for (int s = 0; s < NBATCH; ++s) c += (sdec[s] > b);
        sbat[b] = c;
        wsI[WI_BATCH + b] = c;
    }
    __syncthreads();
    if (b == 0) {
        int run = 0;
        for (int t = 0; t < NSTEP; ++t) { wsI[WI_OFF + t] = run; run += sbat[t]; }
        wsI[WI_P] = run;
    }
}

// ---------------------------------------------------------------- h = 0 (f32 + hi/lo)
__global__ __launch_bounds__(256) void h_init_kernel(float* __restrict__ h,
                                                     unsigned short* __restrict__ h_hi,
                                                     unsigned short* __restrict__ h_lo) {
    int i = blockIdx.x * 256 + threadIdx.x;
    h[i] = 0.f;
    h_hi[i] = 0;
    h_lo[i] = 0;
}

// ---------------------------------------------------------------- gather v by order + RN-split hi/lo
__global__ __launch_bounds__(256) void gather_split_v_kernel(const float* __restrict__ v,
                                                             const int* __restrict__ wsI,
                                                             unsigned short* __restrict__ hi,
                                                             unsigned short* __restrict__ lo) {
    const int r = blockIdx.x;           // 0..4607 : s*36+k
    const int s = r / KREG, k = r % KREG;
    const float* src = v + ((size_t)wsI[WI_ORDER + s] * KREG + k) * VD + threadIdx.x * 8;
    float4 a = *(const float4*)(src);
    float4 b = *(const float4*)(src + 4);
    ushort8v oh, ol;
    float vals[8] = {a.x, a.y, a.z, a.w, b.x, b.y, b.z, b.w};
#pragma unroll
    for (int j = 0; j < 8; ++j) {
        unsigned short h = f2bf(vals[j]);
        oh[j] = h;
        ol[j] = f2bf(vals[j] - bf2f(h));
    }
    size_t off = (size_t)r * VD + threadIdx.x * 8;
    *(ushort8v*)(hi + off) = oh;
    *(ushort8v*)(lo + off) = ol;
}

// ---------------------------------------------------------------- Wfc -> bf16 (padded rows zeroed)
__global__ __launch_bounds__(256) void cvt_wfc_kernel(const float* __restrict__ W,
                                                      unsigned short* __restrict__ dst) {
    size_t i8 = ((size_t)blockIdx.x * 256 + threadIdx.x) * 8;  // over NTOKP*HID
    int row = (int)(i8 >> 10);
    ushort8v o;
    if (row < NTOK) {
        o = cvt8(W + i8);
    } else {
        for (int j = 0; j < 8; ++j) o[j] = 0;
    }
    *(ushort8v*)(dst + i8) = o;
}

// ---------------------------------------------------------------- Wih[:,512:2560] -> bf16 [3072][2048]
__global__ __launch_bounds__(256) void cvt_wih2_kernel(const float* __restrict__ Wih,
                                                       unsigned short* __restrict__ dst) {
    size_t i8 = ((size_t)blockIdx.x * 256 + threadIdx.x) * 8;  // over 3072*2048
    int row = (int)(i8 >> 11);
    int col = (int)(i8 & 2047);
    *(ushort8v*)(dst + i8) = cvt8(Wih + (size_t)row * XIN_D + EMB + col);
}

// ---------------------------------------------------------------- Wv [2048][1024] -> WvT hi/lo [1024][2048]
__global__ __launch_bounds__(256) void trans_split_wv_kernel(const float* __restrict__ W,
                                                             unsigned short* __restrict__ hi,
                                                             unsigned short* __restrict__ lo) {
    __shared__ float t[32][33];
    const int k0 = blockIdx.x * 32, n0 = blockIdx.y * 32;
    const int tx = threadIdx.x & 31, ty = threadIdx.x >> 5;  // ty in [0,8)
#pragma unroll
    for (int i = 0; i < 4; ++i) {
        int r = ty + i * 8;
        t[r][tx] = W[(size_t)(k0 + r) * HID + n0 + tx];
    }
    __syncthreads();
#pragma unroll
    for (int i = 0; i < 4; ++i) {
        int rn = ty + i * 8;
        float x = t[tx][rn];  // = W[k0+tx][n0+rn]
        unsigned short h = f2bf(x);
        unsigned short l = f2bf(x - bf2f(h));
        hi[(size_t)(n0 + rn) * VD + k0 + tx] = h;
        lo[(size_t)(n0 + rn) * VD + k0 + tx] = l;
    }
}

// ---------------------------------------------------------------- Wq [1024][1024] -> Bqh rows 0..1023 (WqT hi/lo)
__global__ __launch_bounds__(256) void trans_split_wq_kernel(const float* __restrict__ W,
                                                             unsigned short* __restrict__ hi,
                                                             unsigned short* __restrict__ lo) {
    __shared__ float t[32][33];
    const int k0 = blockIdx.x * 32, n0 = blockIdx.y * 32;
    const int tx = threadIdx.x & 31, ty = threadIdx.x >> 5;
#pragma unroll
    for (int i = 0; i < 4; ++i) {
        int r = ty + i * 8;
        t[r][tx] = W[(size_t)(k0 + r) * HID + n0 + tx];
    }
    __syncthreads();
#pragma unroll
    for (int i = 0; i < 4; ++i) {
        int rn = ty + i * 8;
        float x = t[tx][rn];  // = W[k0+tx][n0+rn]
        unsigned short h = f2bf(x);
        unsigned short l = f2bf(x - bf2f(h));
        hi[(size_t)(n0 + rn) * HID + k0 + tx] = h;
        lo[(size_t)(n0 + rn) * HID + k0 + tx] = l;
    }
}

// ---------------------------------------------------------------- Whh [3072][1024] -> Bqh rows 1024..4095 (hi/lo)
__global__ __launch_bounds__(256) void split_whh_kernel(const float* __restrict__ W,
                                                        unsigned short* __restrict__ hi,
                                                        unsigned short* __restrict__ lo) {
    size_t i8 = ((size_t)blockIdx.x * 256 + threadIdx.x) * 8;  // over 3072*1024
    ushort8v oh, ol;
    split8(W + i8, oh, ol);
    *(ushort8v*)(hi + i8) = oh;
    *(ushort8v*)(lo + i8) = ol;
}

// ================================================================ MFMA GEMMs
// Tile BM=64 x BN=128, BK=64; 4 waves of 32(M)x64(N).
// LDS: ushort offset row*64 + ((chunk ^ (row&7)) * 8)  (XOR bank swizzle).
// All staged GEMMs software-pipelined: tile k+1's global loads issue before tile k's MFMA.

// ---- pv: pvwbf[row][col] = bf16( relu(vrow . WvT[col] + bv[col]) * wa[col] )
//      576 jobs = nt(8) x mr(72), XCD-grouped so B-panel sharers co-locate.
__global__ __launch_bounds__(256) void pv_mfma_kernel(const unsigned short* __restrict__ Ahi,
                                                      const unsigned short* __restrict__ Alo,
                                                      const unsigned short* __restrict__ Bhi,
                                                      const unsigned short* __restrict__ Blo,
                                                      const float* __restrict__ bv,
                                                      const float* __restrict__ wa,
                                                      unsigned short* __restrict__ pvwbf) {
    const int job = xcd_job(blockIdx.x, 8 * 72);
    const int nt = job / 72, mr = job % 72;
    const int m0 = mr * 64, n0 = nt * 128;
    __shared__ unsigned short sAh[64 * 64], sAl[64 * 64];
    __shared__ unsigned short sBh[128 * 64], sBl[128 * 64];
    const int tid = threadIdx.x;
    const int w = tid >> 6, l = tid & 63;
    const int wm = (w >> 1) * 32, wn = (w & 1) * 64;
    const int lr = l & 15, lq = l >> 4;
    const int s8 = tid & 7, ar0 = tid >> 3;
    const int slot = (s8 ^ (ar0 & 7)) * 8;
    const size_t a0Off = (size_t)(m0 + ar0) * VD + s8 * 8;
    const size_t a1Off = a0Off + (size_t)32 * VD;
    const size_t b0Off = (size_t)(n0 + ar0) * VD + s8 * 8;

    f32x4 acc[2][4] = {};
    // prologue: prefetch tile 0
    ushort8v rah0 = *(const ushort8v*)(Ahi + a0Off);
    ushort8v ral0 = *(const ushort8v*)(Alo + a0Off);
    ushort8v rah1 = *(const ushort8v*)(Ahi + a1Off);
    ushort8v ral1 = *(const ushort8v*)(Alo + a1Off);
    ushort8v rbh0 = *(const ushort8v*)(Bhi + b0Off);
    ushort8v rbl0 = *(const ushort8v*)(Blo + b0Off);
    ushort8v rbh1 = *(const ushort8v*)(Bhi + b0Off + (size_t)32 * VD);
    ushort8v rbl1 = *(const ushort8v*)(Blo + b0Off + (size_t)32 * VD);
    ushort8v rbh2 = *(const ushort8v*)(Bhi + b0Off + (size_t)64 * VD);
    ushort8v rbl2 = *(const ushort8v*)(Blo + b0Off + (size_t)64 * VD);
    ushort8v rbh3 = *(const ushort8v*)(Bhi + b0Off + (size_t)96 * VD);
    ushort8v rbl3 = *(const ushort8v*)(Blo + b0Off + (size_t)96 * VD);

    for (int k0 = 0; k0 < VD; k0 += 64) {
        __syncthreads();
        *(ushort8v*)(sAh + ar0 * 64 + slot) = rah0;
        *(ushort8v*)(sAl + ar0 * 64 + slot) = ral0;
        *(ushort8v*)(sAh + (ar0 + 32) * 64 + slot) = rah1;
        *(ushort8v*)(sAl + (ar0 + 32) * 64 + slot) = ral1;
        *(ushort8v*)(sBh + ar0 * 64 + slot) = rbh0;
        *(ushort8v*)(sBl + ar0 * 64 + slot) = rbl0;
        *(ushort8v*)(sBh + (ar0 + 32) * 64 + slot) = rbh1;
        *(ushort8v*)(sBl + (ar0 + 32) * 64 + slot) = rbl1;
        *(ushort8v*)(sBh + (ar0 + 64) * 64 + slot) = rbh2;
        *(ushort8v*)(sBl + (ar0 + 64) * 64 + slot) = rbl2;
        *(ushort8v*)(sBh + (ar0 + 96) * 64 + slot) = rbh3;
        *(ushort8v*)(sBl + (ar0 + 96) * 64 + slot) = rbl3;
        __syncthreads();
        if (k0 + 64 < VD) {
            const int kn = k0 + 64;
            rah0 = *(const ushort8v*)(Ahi + a0Off + kn);
            ral0 = *(const ushort8v*)(Alo + a0Off + kn);
            rah1 = *(const ushort8v*)(Ahi + a1Off + kn);
            ral1 = *(const ushort8v*)(Alo + a1Off + kn);
            rbh0 = *(const ushort8v*)(Bhi + b0Off + kn);
            rbl0 = *(const ushort8v*)(Blo + b0Off + kn);
            rbh1 = *(const ushort8v*)(Bhi + b0Off + (size_t)32 * VD + kn);
            rbl1 = *(const ushort8v*)(Blo + b0Off + (size_t)32 * VD + kn);
            rbh2 = *(const ushort8v*)(Bhi + b0Off + (size_t)64 * VD + kn);
            rbl2 = *(const ushort8v*)(Blo + b0Off + (size_t)64 * VD + kn);
            rbh3 = *(const ushort8v*)(Bhi + b0Off + (size_t)96 * VD + kn);
            rbl3 = *(const ushort8v*)(Blo + b0Off + (size_t)96 * VD + kn);
        }
        mfma_inner_split(sAh, sAl, sBh, sBl, wm, wn, lr, lq, acc);
    }

#pragma unroll
    for (int m = 0; m < 2; ++m) {
        const int row = m0 + wm + m * 16 + lq * 4;
#pragma unroll
        for (int n = 0; n < 4; ++n) {
            const int col = n0 + wn + n * 16 + lr;
            const float bb = bv[col], ww = wa[col];
#pragma unroll
            for (int i = 0; i < 4; ++i)
                pvwbf[(size_t)(row + i) * HID + col] = f2bf(fmaxf(acc[m][n][i] + bb, 0.f) * ww);
        }
    }
}

// ---- pvw2: PVW2[(s*36+k)][j] = bf16( vhi[row] . wih2bf[j] )  pure bf16, 24 KB LDS.
//      1728 jobs = nt(24) x mr(72), XCD-grouped.
__global__ __launch_bounds__(256) void pvw2_mfma_kernel(const unsigned short* __restrict__ vhi,
                                                        const unsigned short* __restrict__ w2,
                                                        unsigned short* __restrict__ pvw2) {
    const int job = xcd_job(blockIdx.x, 24 * 72);
    const int nt = job / 72, mr = job % 72;
    const int m0 = mr * 64, n0 = nt * 128;
    __shared__ unsigned short sA[64 * 64];
    __shared__ unsigned short sB[128 * 64];
    const int tid = threadIdx.x;
    const int w = tid >> 6, l = tid & 63;
    const int wm = (w >> 1) * 32, wn = (w & 1) * 64;
    const int lr = l & 15, lq = l >> 4;
    const int s8 = tid & 7, ar0 = tid >> 3;
    const int slot = (s8 ^ (ar0 & 7)) * 8;
    const size_t aBase = (size_t)(m0 + ar0) * VD + s8 * 8;
    const size_t bBase = (size_t)(n0 + ar0) * VD + s8 * 8;

    f32x4 acc[2][4] = {};
    // prologue: prefetch tile 0
    ushort8v ra0 = *(const ushort8v*)(vhi + aBase);
    ushort8v ra1 = *(const ushort8v*)(vhi + aBase + (size_t)32 * VD);
    ushort8v rb0 = *(const ushort8v*)(w2 + bBase);
    ushort8v rb1 = *(const ushort8v*)(w2 + bBase + (size_t)32 * VD);
    ushort8v rb2 = *(const ushort8v*)(w2 + bBase + (size_t)64 * VD);
    ushort8v rb3 = *(const ushort8v*)(w2 + bBase + (size_t)96 * VD);

    for (int k0 = 0; k0 < VD; k0 += 64) {
        __syncthreads();
        *(ushort8v*)(sA + ar0 * 64 + slot) = ra0;
        *(ushort8v*)(sA + (ar0 + 32) * 64 + slot) = ra1;
        *(ushort8v*)(sB + ar0 * 64 + slot) = rb0;
        *(ushort8v*)(sB + (ar0 + 32) * 64 + slot) = rb1;
        *(ushort8v*)(sB + (ar0 + 64) * 64 + slot) = rb2;
        *(ushort8v*)(sB + (ar0 + 96) * 64 + slot) = rb3;
        __syncthreads();
        if (k0 + 64 < VD) {
            const int kn = k0 + 64;
            ra0 = *(const ushort8v*)(vhi + aBase + kn);
            ra1 = *(const ushort8v*)(vhi + aBase + (size_t)32 * VD + kn);
            rb0 = *(const ushort8v*)(w2 + bBase + kn);
            rb1 = *(const ushort8v*)(w2 + bBase + (size_t)32 * VD + kn);
            rb2 = *(const ushort8v*)(w2 + bBase + (size_t)64 * VD + kn);
            rb3 = *(const ushort8v*)(w2 + bBase + (size_t)96 * VD + kn);
        }
        mfma_inner_bf16(sA, sB, wm, wn, lr, lq, acc);
    }

#pragma unroll
    for (int m = 0; m < 2; ++m) {
        const int row = m0 + wm + m * 16 + lq * 4;
#pragma unroll
        for (int n = 0; n < 4; ++n) {
            const int col = n0 + wn + n * 16 + lr;
#pragma unroll
            for (int i = 0; i < 4; ++i)
                pvw2[(size_t)(row + i) * G3 + col] = f2bf(acc[m][n][i]);
        }
    }
}

// ---- giE: giE[(t*128+s)][j] = bf16( emb[caption[order[s],t]] . Wih[j, 0:512] )  split-3
__global__ __launch_bounds__(256) void giE_mfma_kernel(const float* __restrict__ emb,
                                                       const int* __restrict__ caption,
                                                       const float* __restrict__ Wih,
                                                       const int* __restrict__ wsI,
                                                       unsigned short* __restrict__ giE) {
    const int m0 = blockIdx.y * 64;   // over 2432
    const int n0 = blockIdx.x * 128;  // over 3072
    __shared__ unsigned short sAh[64 * 64], sAl[64 * 64];
    __shared__ unsigned short sBh[128 * 64], sBl[128 * 64];
    const int tid = threadIdx.x;
    const int w = tid >> 6, l = tid & 63;
    const int wm = (w >> 1) * 32, wn = (w & 1) * 64;
    const int lr = l & 15, lq = l >> 4;
    const int s8 = tid & 7, ar0 = tid >> 3;
    const int slot = (s8 ^ (ar0 & 7)) * 8;
    const int gm0 = m0 + ar0, gm1 = gm0 + 32;
    const int tok0 = caption[wsI[WI_ORDER + (gm0 & 127)] * ML + (gm0 >> 7)];
    const int tok1 = caption[wsI[WI_ORDER + (gm1 & 127)] * ML + (gm1 >> 7)];
    const float* aR0 = emb + (size_t)tok0 * EMB + s8 * 8;
    const float* aR1 = emb + (size_t)tok1 * EMB + s8 * 8;
    const float* bR0 = Wih + (size_t)(n0 + ar0) * XIN_D + s8 * 8;

    f32x4 acc[2][4] = {};

    for (int k0 = 0; k0 < EMB; k0 += 64) {
        ushort8v ah0, al0, ah1, al1;
        split8(aR0 + k0, ah0, al0);
        split8(aR1 + k0, ah1, al1);
        ushort8v bh_[4], bl_[4];
#pragma unroll
        for (int j = 0; j < 4; ++j)
            split8(bR0 + (size_t)j * 32 * XIN_D + k0, bh_[j], bl_[j]);
        __syncthreads();
        *(ushort8v*)(sAh + ar0 * 64 + slot) = ah0;
        *(ushort8v*)(sAl + ar0 * 64 + slot) = al0;
        *(ushort8v*)(sAh + (ar0 + 32) * 64 + slot) = ah1;
        *(ushort8v*)(sAl + (ar0 + 32) * 64 + slot) = al1;
#pragma unroll
        for (int j = 0; j < 4; ++j) {
            *(ushort8v*)(sBh + (ar0 + j * 32) * 64 + slot) = bh_[j];
            *(ushort8v*)(sBl + (ar0 + j * 32) * 64 + slot) = bl_[j];
        }
        __syncthreads();
        mfma_inner_split(sAh, sAl, sBh, sBl, wm, wn, lr, lq, acc);
    }

#pragma unroll
    for (int m = 0; m < 2; ++m) {
        const int row = m0 + wm + m * 16 + lq * 4;
#pragma unroll
        for (int n = 0; n < 4; ++n) {
            const int col = n0 + wn + n * 16 + lr;
#pragma unroll
            for (int i = 0; i < 4; ++i)
                giE[(size_t)(row + i) * G3 + col] = f2bf(acc[m][n][i]);
        }
    }
}

// ---- qh(t): split-K=4 partials into qhp (256 blocks); h pre-split hi/lo; pipelined
__global__ __launch_bounds__(256) void qh_kernel(const unsigned short* __restrict__ h_hi,
                                                 const unsigned short* __restrict__ h_lo,
                                                 const unsigned short* __restrict__ Bhi,
                                                 const unsigned short* __restrict__ Blo,
                                                 const int* __restrict__ wsI, int tq,
                                                 float* __restrict__ qhp) {
    if (tq >= NSTEP) return;
    __shared__ unsigned short lds[24576];  // 48 KB
    const int tid = threadIdx.x;
    const int w = tid >> 6, l = tid & 63;
    const int wm = (w >> 1) * 32, wn = (w & 1) * 64;
    const int lr = l & 15, lq = l >> 4;
    const int s8 = tid & 7, ar0 = tid >> 3;
    const int slot = (s8 ^ (ar0 & 7)) * 8;
    const int bx = blockIdx.x;
    const int nt = bx & 31, mt = (bx >> 5) & 1, sl = bx >> 6;  // sl in [0,4)
    const int nb = wsI[WI_BATCH + tq];
    const int m0 = mt * 64;
    if (m0 >= nb) return;
    const int n0 = nt * 128;
    const int kb = sl * QH_KPER;
    unsigned short* sAh = lds;
    unsigned short* sAl = lds + 4096;
    unsigned short* sBh = lds + 8192;
    unsigned short* sBl = lds + 16384;
    const size_t aOff = (size_t)(m0 + ar0) * HID + s8 * 8;
    const size_t bOff = (size_t)(n0 + ar0) * HID + s8 * 8;

    f32x4 acc[2][4] = {};
    // prologue: prefetch tile kb
    ushort8v rah0 = *(const ushort8v*)(h_hi + aOff + kb);
    ushort8v ral0 = *(const ushort8v*)(h_lo + aOff + kb);
    ushort8v rah1 = *(const ushort8v*)(h_hi + aOff + (size_t)32 * HID + kb);
    ushort8v ral1 = *(const ushort8v*)(h_lo + aOff + (size_t)32 * HID + kb);
    ushort8v rbh0 = *(const ushort8v*)(Bhi + bOff + kb);
    ushort8v rbl0 = *(const ushort8v*)(Blo + bOff + kb);
    ushort8v rbh1 = *(const ushort8v*)(Bhi + bOff + (size_t)32 * HID + kb);
    ushort8v rbl1 = *(const ushort8v*)(Blo + bOff + (size_t)32 * HID + kb);
    ushort8v rbh2 = *(const ushort8v*)(Bhi + bOff + (size_t)64 * HID + kb);
    ushort8v rbl2 = *(const ushort8v*)(Blo + bOff + (size_t)64 * HID + kb);
    ushort8v rbh3 = *(const ushort8v*)(Bhi + bOff + (size_t)96 * HID + kb);
    ushort8v rbl3 = *(const ushort8v*)(Blo + bOff + (size_t)96 * HID + kb);

    for (int k0 = kb; k0 < kb + QH_KPER; k0 += 64) {
        __syncthreads();
        *(ushort8v*)(sAh + ar0 * 64 + slot) = rah0;
        *(ushort8v*)(sAl + ar0 * 64 + slot) = ral0;
        *(ushort8v*)(sAh + (ar0 + 32) * 64 + slot) = rah1;
        *(ushort8v*)(sAl + (ar0 + 32) * 64 + slot) = ral1;
        *(ushort8v*)(sBh + ar0 * 64 + slot) = rbh0;
        *(ushort8v*)(sBl + ar0 * 64 + slot) = rbl0;
        *(ushort8v*)(sBh + (ar0 + 32) * 64 + slot) = rbh1;
        *(ushort8v*)(sBl + (ar0 + 32) * 64 + slot) = rbl1;
        *(ushort8v*)(sBh + (ar0 + 64) * 64 + slot) = rbh2;
        *(ushort8v*)(sBl + (ar0 + 64) * 64 + slot) = rbl2;
        *(ushort8v*)(sBh + (ar0 + 96) * 64 + slot) = rbh3;
        *(ushort8v*)(sBl + (ar0 + 96) * 64 + slot) = rbl3;
        __syncthreads();
        if (k0 + 64 < kb + QH_KPER) {
            const int kn = k0 + 64;
            rah0 = *(const ushort8v*)(h_hi + aOff + kn);
            ral0 = *(const ushort8v*)(h_lo + aOff + kn);
            rah1 = *(const ushort8v*)(h_hi + aOff + (size_t)32 * HID + kn);
            ral1 = *(const ushort8v*)(h_lo + aOff + (size_t)32 * HID + kn);
            rbh0 = *(const ushort8v*)(Bhi + bOff + kn);
            rbl0 = *(const ushort8v*)(Blo + bOff + kn);
            rbh1 = *(const ushort8v*)(Bhi + bOff + (size_t)32 * HID + kn);
            rbl1 = *(const ushort8v*)(Blo + bOff + (size_t)32 * HID + kn);
            rbh2 = *(const ushort8v*)(Bhi + bOff + (size_t)64 * HID + kn);
            rbl2 = *(const ushort8v*)(Blo + bOff + (size_t)64 * HID + kn);
            rbh3 = *(const ushort8v*)(Bhi + bOff + (size_t)96 * HID + kn);
            rbl3 = *(const ushort8v*)(Blo + bOff + (size_t)96 * HID + kn);
        }
        mfma_inner_split(sAh, sAl, sBh, sBl, wm, wn, lr, lq, acc);
    }
#pragma unroll
    for (int m = 0; m < 2; ++m) {
        const int row = m0 + wm + m * 16 + lq * 4;
#pragma unroll
        for (int n = 0; n < 4; ++n) {
            const int col = n0 + wn + n * 16 + lr;
#pragma unroll
            for (int i = 0; i < 4; ++i) {
                int r = row + i;
                if (r < nb) qhp[((size_t)(sl * NBATCH) + r) * NQH + col] = acc[m][n][i];
            }
        }
    }
}

// ---- batched logits over all steps, BN=128, XCD-grouped, SOFTWARE-PIPELINED:
//      tile k+1's global loads issue before tile k's MFMA (latency hides under MFMA+barrier).
__global__ __launch_bounds__(256) void big_logits_kernel(const unsigned short* __restrict__ hbf_all,
                                                         const unsigned short* __restrict__ Wbf,
                                                         const float* __restrict__ bfc,
                                                         const int* __restrict__ wsI,
                                                         float* __restrict__ out) {
    const int job = xcd_job(blockIdx.x, 38 * 157);
    const int nt = job / 38;
    const int x = job % 38;
    const int t = x >> 1, mt = x & 1;
    const int nb = wsI[WI_BATCH + t];
    const int m0 = mt * 64;
    if (m0 >= nb) return;
    const int n0 = nt * 128;
    __shared__ unsigned short lds[12288];  // 24 KB
    unsigned short* sA = lds;
    unsigned short* sB = lds + 4096;
    const int tid = threadIdx.x;
    const int w = tid >> 6, l = tid & 63;
    const int wm = (w >> 1) * 32, wn = (w & 1) * 64;
    const int lr = l & 15, lq = l >> 4;
    const int s8 = tid & 7, ar0 = tid >> 3;
    const int slot = (s8 ^ (ar0 & 7)) * 8;
    const unsigned short* hbf = hbf_all + (size_t)t * NBATCH * HID;
    const size_t aBase = (size_t)(m0 + ar0) * HID + s8 * 8;
    const size_t bBase = (size_t)(n0 + ar0) * HID + s8 * 8;

    f32x4 acc[2][4] = {};
    // prologue: prefetch tile 0
    ushort8v ra0 = *(const ushort8v*)(hbf + aBase);
    ushort8v ra1 = *(const ushort8v*)(hbf + aBase + (size_t)32 * HID);
    ushort8v rb0 = *(const ushort8v*)(Wbf + bBase);
    ushort8v rb1 = *(const ushort8v*)(Wbf + bBase + (size_t)32 * HID);
    ushort8v rb2 = *(const ushort8v*)(Wbf + bBase + (size_t)64 * HID);
    ushort8v rb3 = *(const ushort8v*)(Wbf + bBase + (size_t)96 * HID);

#pragma unroll
    for (int k0 = 0; k0 < HID; k0 += 64) {
        __syncthreads();   // all waves done consuming LDS from previous tile
        *(ushort8v*)(sA + ar0 * 64 + slot) = ra0;
        *(ushort8v*)(sA + (ar0 + 32) * 64 + slot) = ra1;
        *(ushort8v*)(sB + ar0 * 64 + slot) = rb0;
        *(ushort8v*)(sB + (ar0 + 32) * 64 + slot) = rb1;
        *(ushort8v*)(sB + (ar0 + 64) * 64 + slot) = rb2;
        *(ushort8v*)(sB + (ar0 + 96) * 64 + slot) = rb3;
        __syncthreads();
        if (k0 + 64 < HID) {   // prefetch next tile; flies under the 8 MFMAs below
            const int kn = k0 + 64;
            ra0 = *(const ushort8v*)(hbf + aBase + kn);
            ra1 = *(const ushort8v*)(hbf + aBase + (size_t)32 * HID + kn);
            rb0 = *(const ushort8v*)(Wbf + bBase + kn);
            rb1 = *(const ushort8v*)(Wbf + bBase + (size_t)32 * HID + kn);
            rb2 = *(const ushort8v*)(Wbf + bBase + (size_t)64 * HID + kn);
            rb3 = *(const ushort8v*)(Wbf + bBase + (size_t)96 * HID + kn);
        }
        mfma_inner_bf16(sA, sB, wm, wn, lr, lq, acc);
    }
    const int offt = wsI[WI_OFF + t];
#pragma unroll
    for (int m = 0; m < 2; ++m) {
        const int row = m0 + wm + m * 16 + lq * 4;
#pragma unroll
        for (int n = 0; n < 4; ++n) {
            const int col = n0 + wn + n * 16 + lr;
            if (col < NTOK) {
                const float bb = bfc[col];
#pragma unroll
                for (int i = 0; i < 4; ++i) {
                    int r = row + i;
                    if (r < nb) out[(size_t)(offt + r) * NTOK + col] = acc[m][n][i] + bb;
                }
            }
        }
    }
}

// ---------------------------------------------------------------- AG: scores + softmax + gisum + GRU
//      grid = 2*NBATCH: block (s, half); phases A-C duplicated per half (cheap),
//      phase D covers HID/2 columns -> 2x CU coverage on the dominant pvw2 stream.
__global__ __launch_bounds__(256) void ag_kernel(const float* __restrict__ qhp,
                                                 const float* __restrict__ bq,
                                                 const unsigned short* __restrict__ pvwbf,
                                                 const unsigned short* __restrict__ pvw2,
                                                 const unsigned short* __restrict__ giE,
                                                 const float* __restrict__ bih,
                                                 const float* __restrict__ bhh,
                                                 const int* __restrict__ wsI, int t,
                                                 float* __restrict__ h,
                                                 unsigned short* __restrict__ h_hi,
                                                 unsigned short* __restrict__ h_lo,
                                                 unsigned short* __restrict__ hbf_all) {
    const int nb = wsI[WI_BATCH + t];
    const int s = blockIdx.x >> 1;
    const int half = blockIdx.x & 1;
    if (s >= nb) return;
    const int tid = threadIdx.x;
    __shared__ float pq_s[HID];
    __shared__ float sc[64];
    unsigned short* hbfA = hbf_all + (size_t)t * NBATCH * HID;

    // phase A: pq = relu(bq + sum of QH_SK partials)
    for (int j = tid; j < HID; j += 256) {
        float a = bq[j];
#pragma unroll
        for (int sl = 0; sl < QH_SK; ++sl) a += qhp[(size_t)(sl * NBATCH + s) * NQH + j];
        pq_s[j] = fmaxf(a, 0.f);
    }
    __syncthreads();

    // phase B: 36 attention scores (vectorized ushort8 loads)
    const int w = tid >> 6, lane = tid & 63;
    for (int k = w; k < KREG; k += 4) {
        const unsigned short* pr = pvwbf + ((size_t)s * KREG + k) * HID;
        float a = 0.f;
#pragma unroll
        for (int c = 0; c < 2; ++c) {
            const int hh = (lane + 64 * c) * 8;
            ushort8v p8 = *(const ushort8v*)(pr + hh);
            float4 q0 = *(const float4*)(pq_s + hh);
            float4 q1 = *(const float4*)(pq_s + hh + 4);
            a += bf2f(p8[0]) * q0.x + bf2f(p8[1]) * q0.y + bf2f(p8[2]) * q0.z + bf2f(p8[3]) * q0.w;
            a += bf2f(p8[4]) * q1.x + bf2f(p8[5]) * q1.y + bf2f(p8[6]) * q1.z + bf2f(p8[7]) * q1.w;
        }
#pragma unroll
        for (int o = 32; o > 0; o >>= 1) a += __shfl_down(a, o);
        if (lane == 0) sc[k] = a;
    }
    __syncthreads();

    // phase C: softmax over 36
    if (tid < 64) {
        float x = (tid < KREG) ? sc[tid] : -1e30f;
        float m = x;
#pragma unroll
        for (int o = 32; o > 0; o >>= 1) m = fmaxf(m, __shfl_xor(m, o));
        float e = (tid < KREG) ? expf(x - m) : 0.f;
        float sum = e;
#pragma unroll
        for (int o = 32; o > 0; o >>= 1) sum += __shfl_xor(sum, o);
        if (tid < KREG) sc[tid] = e / sum;
    }
    __syncthreads();

    // phase D (tid<128): gisum (giE + att-weighted PVW2) + GRU gates over this half's 512 cols
    if (tid < 128) {
        const int j0 = half * 512 + tid * 4;
        float accR[4], accZ[4], accN[4];
        {
            const unsigned short* ge = giE + ((size_t)(t * NBATCH) + s) * G3;
            ushort4v r4 = *(const ushort4v*)(ge + j0);
            ushort4v z4 = *(const ushort4v*)(ge + HID + j0);
            ushort4v n4 = *(const ushort4v*)(ge + 2 * HID + j0);
#pragma unroll
            for (int i = 0; i < 4; ++i) {
                accR[i] = bf2f(r4[i]);
                accZ[i] = bf2f(z4[i]);
                accN[i] = bf2f(n4[i]);
            }
        }
#pragma unroll 4
        for (int k = 0; k < KREG; ++k) {
            const unsigned short* p = pvw2 + ((size_t)s * KREG + k) * G3;
            const float ak = sc[k];
            ushort4v r4 = *(const ushort4v*)(p + j0);
            ushort4v z4 = *(const ushort4v*)(p + HID + j0);
            ushort4v n4 = *(const ushort4v*)(p + 2 * HID + j0);
#pragma unroll
            for (int i = 0; i < 4; ++i) {
                accR[i] += ak * bf2f(r4[i]);
                accZ[i] += ak * bf2f(z4[i]);
                accN[i] += ak * bf2f(n4[i]);
            }
        }
#pragma unroll
        for (int i = 0; i < 4; ++i) {
            const int j = j0 + i;
            float ghr = bhh[j], ghz = bhh[j + HID], ghn = bhh[j + 2 * HID];
#pragma unroll
            for (int sl = 0; sl < QH_SK; ++sl) {
                const float* p = qhp + (size_t)(sl * NBATCH + s) * NQH + HID;
                ghr += p[j]; ghz += p[j + HID]; ghn += p[j + 2 * HID];
            }
            float gir = bih[j] + accR[i];
            float giz = bih[j + HID] + accZ[i];
            float gin = bih[j + 2 * HID] + accN[i];
            float r = sigmoidf_(gir + ghr);
            float z = sigmoidf_(giz + ghz);
            float n = tanhf(gin + r * ghn);
            size_t idx = (size_t)s * HID + j;
            float hn = (1.f - z) * n + z * h[idx];
            h[idx] = hn;
            hbfA[idx] = f2bf(hn);
            // trunc-hi + RN-lo split (identical to split8 numerics) for next qh
            unsigned int bits = __float_as_uint(hn);
            unsigned short hh = (unsigned short)(bits >> 16);
            h_hi[idx] = hh;
            h_lo[idx] = f2bf(hn - __uint_as_float(bits & 0xFFFF0000u));
        }
    }
}

// ---------------------------------------------------------------- in-place softmax over time dim
__global__ __launch_bounds__(256) void softmax_time_kernel(const int* __restrict__ wsI,
                                                           float* __restrict__ out) {
    const int n = blockIdx.x * 256 + threadIdx.x;
    if (n >= NTOK) return;
    const int s = blockIdx.y;
    const int dc = wsI[WI_DEC + s];
    float l[NSTEP];
    float m = 0.f;
#pragma unroll
    for (int t = 0; t < NSTEP; ++t) {
        float val = -1e30f;
        if (t < dc) val = out[(size_t)(wsI[WI_OFF + t] + s) * NTOK + n];
        l[t] = val;
        m = fmaxf(m, val);
    }
    float denom = (float)(ML - dc) * expf(-m);
    float e[NSTEP];
#pragma unroll
    for (int t = 0; t < NSTEP; ++t) {
        e[t] = expf(l[t] - m);
        if (t < dc) denom += e[t];
    }
    const float inv = 1.f / denom;
#pragma unroll
    for (int t = 0; t < NSTEP; ++t)
        if (t < dc) {
            float val = e[t] * inv;
            __builtin_nontemporal_store(val, &out[(size_t)(wsI[WI_OFF + t] + s) * NTOK + n]);
        }
}

// ---------------------------------------------------------------- targets
__global__ __launch_bounds__(128) void target_kernel(const int* __restrict__ caption,
                                                     const int* __restrict__ wsI,
                                                     float* __restrict__ out) {
    const int t = blockIdx.x, s = threadIdx.x;
    if (s < wsI[WI_BATCH + t]) {
        size_t base = (size_t)wsI[WI_P] * NTOK;
        out[base + wsI[WI_OFF + t] + s] = (float)caption[wsI[WI_ORDER + s] * ML + t + 1];
    }
}

// ---------------------------------------------------------------- launch
extern "C" void kernel_launch(void* const* d_in, const int* in_sizes, int n_in,
                              void* d_out, int out_size, void* d_ws, size_t ws_size,
                              hipStream_t stream) {
    const float* v       = (const float*)d_in[0];
    const int*   caption = (const int*)d_in[1];
    const int*   cap_len = (const int*)d_in[2];
    const float* emb     = (const float*)d_in[3];
    const float* Wv      = (const float*)d_in[4];
    const float* bv      = (const float*)d_in[5];
    const float* Wq      = (const float*)d_in[6];
    const float* bq      = (const float*)d_in[7];
    const float* wa      = (const float*)d_in[8];
    // d_in[9] = ba: dropped (softmax shift-invariant)
    const float* Wih     = (const float*)d_in[10];
    const float* Whh     = (const float*)d_in[11];
    const float* bih     = (const float*)d_in[12];
    const float* bhh     = (const float*)d_in[13];
    const float* Wfc     = (const float*)d_in[14];
    const float* bfc     = (const float*)d_in[15];
    float* out = (float*)d_out;

    // workspace layout (~117 MB, lifetime-overlaid regions X/Y/Z)
    int* wsI = (int*)d_ws;
    unsigned short* base    = (unsigned short*)((char*)d_ws + 4096);
    unsigned short* pvwbf   = base;                       //  4,718,592 us
    unsigned short* pvw2    = pvwbf + 4718592;            // 14,155,776 us
    unsigned short* hbf_all = pvw2 + 14155776;            //  2,490,368 us (19 steps)
    unsigned short* X       = hbf_all + 2490368;          // 20,578,304 us (NTOKP*HID)
    unsigned short* Y       = X + 20578304;               //  8,388,608 us
    unsigned short* Z       = Y + 8388608;                //  7,471,104 us
    float* h = (float*)(Z + 7471104);                     //    131,072 f
    unsigned short* h_hi = (unsigned short*)(h + 131072); //    131,072 us
    unsigned short* h_lo = h_hi + 131072;                 //    131,072 us
    // region views (disjoint lifetimes):
    unsigned short* vhi    = X;              // pre-phase (until pvw2 done)
    unsigned short* vlo    = X + 9437184;
    float*          qhp    = (float*)X;      // loop phase (4*128*4096 f = 8 MB)
    unsigned short* Wfcbf  = X;              // post-loop (cvt_wfc kills qhp)
    unsigned short* wvthi  = Y;              // pre-phase (pv)
    unsigned short* wvtlo  = Y + 2097152;
    unsigned short* bqh_hi = Y;              // from trans_wq on (kills wvt)
    unsigned short* bqh_lo = Y + 4194304;
    unsigned short* wih2bf = Z;              // pre-phase (pvw2)
    unsigned short* giE    = Z;              // from giE_mfma on (kills wih2bf)

    prep_kernel<<<1, 128, 0, stream>>>(cap_len, wsI);
    h_init_kernel<<<(NBATCH * HID) / 256, 256, 0, stream>>>(h, h_hi, h_lo);
    gather_split_v_kernel<<<NBATCH * KREG, 256, 0, stream>>>(v, wsI, vhi, vlo);
    trans_split_wv_kernel<<<dim3(VD / 32, HID / 32), 256, 0, stream>>>(Wv, wvthi, wvtlo);
    cvt_wih2_kernel<<<(G3 * VD / 8) / 256, 256, 0, stream>>>(Wih, wih2bf);
    pv_mfma_kernel<<<8 * 72, 256, 0, stream>>>(vhi, vlo, wvthi, wvtlo, bv, wa, pvwbf);
    pvw2_mfma_kernel<<<24 * 72, 256, 0, stream>>>(vhi, wih2bf, pvw2);
    // wvt dead -> bqh; wih2bf dead -> giE; vhi/vlo dead -> qhp
    trans_split_wq_kernel<<<dim3(HID / 32, HID / 32), 256, 0, stream>>>(Wq, bqh_hi, bqh_lo);
    split_whh_kernel<<<(G3 * HID / 8) / 256, 256, 0, stream>>>(
        Whh, bqh_hi + (size_t)HID * HID, bqh_lo + (size_t)HID * HID);
    giE_mfma_kernel<<<dim3(G3 / 128, (NSTEP * NBATCH) / 64), 256, 0, stream>>>(
        emb, caption, Wih, wsI, giE);

    // prologue qh(0) (h == 0 -> zero partials)
    qh_kernel<<<64 * QH_SK, 256, 0, stream>>>(h_hi, h_lo, bqh_hi, bqh_lo, wsI, 0, qhp);

    for (int t = 0; t < NSTEP; ++t) {
        ag_kernel<<<NBATCH * 2, 256, 0, stream>>>(qhp, bq, pvwbf, pvw2, giE, bih, bhh, wsI, t,
                                                  h, h_hi, h_lo, hbf_all);
        if (t + 1 < NSTEP)
            qh_kernel<<<64 * QH_SK, 256, 0, stream>>>(h_hi, h_lo, bqh_hi, bqh_lo, wsI, t + 1, qhp);
    }

    // qhp dead -> Wfcbf
    cvt_wfc_kernel<<<((size_t)NTOKP * HID / 8) / 256, 256, 0, stream>>>(Wfc, Wfcbf);
    big_logits_kernel<<<38 * 157, 256, 0, stream>>>(hbf_all, Wfcbf, bfc, wsI, out);
    softmax_time_kernel<<<dim3((NTOK + 255) / 256, NBATCH), 256, 0, stream>>>(wsI, out);
    target_kernel<<<NSTEP, 128, 0, stream>>>(caption, wsI, out);
    (void)in_sizes; (void)n_in; (void)out_size; (void)ws_size;
}